// Round 4
// baseline (227.609 us; speedup 1.0000x reference)
//
#include <hip/hip_runtime.h>
#include <math.h>

typedef __attribute__((ext_vector_type(8))) short short8;
typedef __attribute__((ext_vector_type(4))) float f32x4;

#define NTOK 32768          // B*L
#define DDIM 1024
#define HDIM 64
#define NB 16
#define LN_EPS 1e-5f

#define IDX_OFF ((size_t)NTOK * NB)            // 524288
#define AUX_OFF (IDX_OFF + (size_t)NTOK * 2)   // 589824
#define WT_OFF  (AUX_OFF + 1)                  // 589825

// ws (float) layout:
//   [0:16)  cnt accum   [16:32) Psum accum   [32] completion counter (uint)
//   [64:128)  csg = colsum(gamma*W1)   [128:192) csb = colsum(beta*W1)
//   [4352 : +98304)   B-pack: 3 terms x 32 ksteps x 4 ntiles x 64 lanes x 4 dw
//   [102656 : +8192)  per-block partials: 256 rows x [0:16 cnt | 16:32 Psum]
#define CS_F   64
#define BP_F   4352
#define PART_F 102656

__device__ __forceinline__ short8 as_s8(uint4 u) {
    union { uint4 u; short8 s; } x; x.u = u; return x.s;
}

// async global->LDS, 16B per lane. LDS dest is wave-uniform base + lane*16;
// global src is per-lane.
__device__ __forceinline__ void gld16(const void* g, float* l) {
    __builtin_amdgcn_global_load_lds(
        (const __attribute__((address_space(1))) void*)g,
        (__attribute__((address_space(3))) void*)l, 16, 0, 0);
}

// Fused: B-pack (3-term bf16 split of gamma*W1, MFMA B-frag order) + final
// colsums of gamma*W1 / beta*W1 via atomicAdd (ws[CS_F..] pre-zeroed).
__global__ void pack_kernel(const float* __restrict__ W1,
                            const float* __restrict__ gamma,
                            const float* __restrict__ beta,
                            float* __restrict__ ws) {
    __shared__ float sg[4][64];
    __shared__ float sb[4][64];
    const int s = blockIdx.x;           // k-range 32s..32s+31
    const int t = threadIdx.x;          // 256

    {   // cs partials
        const int j = t & 63, p = t >> 6;
        float ag = 0.f, ab = 0.f;
        for (int kk = 0; kk < 8; ++kk) {
            const int k = s * 32 + p * 8 + kk;
            const float w = W1[k * HDIM + j];
            ag += gamma[k] * w;
            ab += beta[k] * w;
        }
        sg[p][j] = ag;
        sb[p][j] = ab;
    }

    {   // B pack
        unsigned int* bp = (unsigned int*)(ws + BP_F);
        const int n = t >> 6;           // n-tile
        const int l = t & 63;           // frag lane
        const int q = l >> 4, c = l & 15;
        const int col = n * 16 + c;
        unsigned int uh[8], um[8], ul[8];
#pragma unroll
        for (int j = 0; j < 8; ++j) {
            const int k = s * 32 + q * 8 + j;
            const float w = gamma[k] * W1[k * HDIM + col];
            const unsigned int hb = __float_as_uint(w) & 0xFFFF0000u;
            const float r = w - __uint_as_float(hb);
            const unsigned int mb = __float_as_uint(r) & 0xFFFF0000u;
            const float r2 = r - __uint_as_float(mb);
            const unsigned int lb = __float_as_uint(r2) & 0xFFFF0000u;
            uh[j] = hb >> 16; um[j] = mb >> 16; ul[j] = lb >> 16;
        }
        const int base = ((s * 4 + n) * 64 + l) * 4;
#pragma unroll
        for (int d = 0; d < 4; ++d) {
            bp[base + d]         = uh[2 * d] | (uh[2 * d + 1] << 16);
            bp[32768 + base + d] = um[2 * d] | (um[2 * d + 1] << 16);
            bp[65536 + base + d] = ul[2 * d] | (ul[2 * d + 1] << 16);
        }
    }
    __syncthreads();
    if (t < 64) {
        atomicAdd(&ws[CS_F + t],      sg[0][t] + sg[1][t] + sg[2][t] + sg[3][t]);
        atomicAdd(&ws[CS_F + 64 + t], sb[0][t] + sb[1][t] + sb[2][t] + sb[3][t]);
    }
}

// 3-term truncated-bf16 split of 8 floats + LN-stat accumulation.
__device__ __forceinline__ void split8(const f32x4 a0, const f32x4 a1,
                                       short8& AH, short8& AM, short8& AL,
                                       float& s1, float& s2) {
    const float v[8] = {a0.x, a0.y, a0.z, a0.w, a1.x, a1.y, a1.z, a1.w};
    unsigned int ph[4], pm[4], pl[4];
#pragma unroll
    for (int d = 0; d < 4; ++d) {
        const float v0 = v[2 * d], v1 = v[2 * d + 1];
        const unsigned int h0 = __float_as_uint(v0) & 0xFFFF0000u;
        const unsigned int h1 = __float_as_uint(v1) & 0xFFFF0000u;
        const float r0 = v0 - __uint_as_float(h0);
        const float r1 = v1 - __uint_as_float(h1);
        const unsigned int m0 = __float_as_uint(r0) & 0xFFFF0000u;
        const unsigned int m1 = __float_as_uint(r1) & 0xFFFF0000u;
        const float q0 = r0 - __uint_as_float(m0);
        const float q1 = r1 - __uint_as_float(m1);
        ph[d] = (h0 >> 16) | h1;
        pm[d] = (m0 >> 16) | m1;
        pl[d] = (__float_as_uint(q0) >> 16) | (__float_as_uint(q1) & 0xFFFF0000u);
        s1 += v0 + v1;
        s2 = fmaf(v0, v0, fmaf(v1, v1, s2));
    }
    AH = as_s8(make_uint4(ph[0], ph[1], ph[2], ph[3]));
    AM = as_s8(make_uint4(pm[0], pm[1], pm[2], pm[3]));
    AL = as_s8(make_uint4(pl[0], pl[1], pl[2], pl[3]));
}

#define MFMA6(ACC, AH, AM, AL, BH, BM, BL)                                        \
    ACC = __builtin_amdgcn_mfma_f32_16x16x32_bf16(AH, as_s8(BH), ACC, 0, 0, 0);   \
    ACC = __builtin_amdgcn_mfma_f32_16x16x32_bf16(AH, as_s8(BM), ACC, 0, 0, 0);   \
    ACC = __builtin_amdgcn_mfma_f32_16x16x32_bf16(AM, as_s8(BH), ACC, 0, 0, 0);   \
    ACC = __builtin_amdgcn_mfma_f32_16x16x32_bf16(AH, as_s8(BL), ACC, 0, 0, 0);   \
    ACC = __builtin_amdgcn_mfma_f32_16x16x32_bf16(AM, as_s8(BM), ACC, 0, 0, 0);   \
    ACC = __builtin_amdgcn_mfma_f32_16x16x32_bf16(AL, as_s8(BH), ACC, 0, 0, 0);

// rule-#18 fences around hand-managed waits
#define WAITV(N)                                                   \
    asm volatile("s_waitcnt vmcnt(" #N ")" ::: "memory");          \
    __builtin_amdgcn_sched_barrier(0)

#define BARRIER_PUB()                                              \
    asm volatile("s_waitcnt vmcnt(4) lgkmcnt(0)" ::: "memory");    \
    __builtin_amdgcn_s_barrier();                                  \
    asm volatile("" ::: "memory");                                 \
    __builtin_amdgcn_sched_barrier(0)

// Block = 128 tokens, 8 waves; wave wv owns tokens [wv*16, +16) and iterates
// the FULL K=1024 as 16 chunks x 2 k-steps. All prior variants were capped at
// ~850 GB/s by Little's law (~0.5-1 KB of x-loads in flight per CU: per-step
// __syncthreads drained vmcnt(0) 32x per pass). Here both A (per-wave 4 KB
// chunk) and B (shared 24 KB chunk) are staged with async global_load_lds and
// COUNTED vmcnt — vmcnt(7) before consuming A, vmcnt(4)+barrier to publish B,
// never vmcnt(0) in the loop — keeping ~32 KB/CU in flight during compute ->
// HBM-throughput-bound (~26 us for the 128 MB x-stream) instead of
// latency-bound (~78 us).
// LDS (floats): Abuf [2][8 waves][4 slots][256] = 16384 | Bbuf [2][2 st][3
// term][4 n][256] = 12288. Total 28672 fl = 112 KB -> 1 block/CU, 2 waves/SIMD.
// Epilogue arrays alias the (dead) staging buffers after the post-loop sync.
#define A_F 0
#define B_F 16384
__global__ __launch_bounds__(512, 2)
void router_main(const float* __restrict__ x,
                 const float* __restrict__ ws_ro,       // csg/csb
                 const unsigned int* __restrict__ bp,   // packed B frags
                 const float* __restrict__ W2,
                 float* __restrict__ part,
                 float* __restrict__ out) {
    __shared__ __align__(16) float smem[28672];
    // epilogue aliases (valid only after the post-loop __syncthreads):
    float* hlds = smem;            // [8 waves][16 tok][65] = 8320
    float* w2l  = smem + 8320;     // [64][16] = 1024
    float* llds = smem + 9344;     // [128 tok][20] = 2560
    float* cntl = smem + 11904;    // [16]

    const int t    = threadIdx.x;
    const int wv   = t >> 6;                 // 0..7
    const int lane = t & 63;
    const int q = lane >> 4, c = lane & 15;
    const int tok0 = blockIdx.x * 128;
    const int tokw = tok0 + wv * 16;

    // per-lane colsum constants (col = n*16 + c)
    float csg[4], csb[4];
#pragma unroll
    for (int n = 0; n < 4; ++n) {
        csg[n] = ws_ro[CS_F + n * 16 + c];
        csb[n] = ws_ro[CS_F + 64 + n * 16 + c];
    }

    // B-stage share for this wave: idx = wv*3+i in [0,24) -> (st, term, n)
    const int bidx0 = wv * 3;
    // A source base for this wave's 16 tokens (lane (q,c) -> token c)
    const float* xsrc = x + (size_t)(tokw + c) * DDIM + q * 8;

#define STAGE_B(CI)                                                              \
    {                                                                            \
        float* dst = smem + B_F + ((CI) & 1) * 6144;                             \
        _Pragma("unroll")                                                        \
        for (int i = 0; i < 3; ++i) {                                            \
            const int idx = bidx0 + i;                                           \
            const int st = (idx >= 12) ? 1 : 0;                                  \
            const int rem = idx - st * 12;                                       \
            const int term = rem >> 2, n = rem & 3;                              \
            gld16(bp + term * 32768 + (2 * (CI) + st) * 1024 + n * 256 + lane*4, \
                  dst + st * 3072 + term * 1024 + n * 256);                      \
        }                                                                        \
    }
#define STAGE_A(CI)                                                              \
    {                                                                            \
        float* dst = smem + A_F + ((CI) & 1) * 8192 + wv * 1024;                 \
        const float* src = xsrc + (2 * (CI)) * 32;                               \
        _Pragma("unroll")                                                        \
        for (int j = 0; j < 4; ++j)                                              \
            gld16(src + (j >> 1) * 32 + (j & 1) * 4, dst + j * 256);             \
    }

    // prologue: stage chunk 0 (B cross-wave published by barrier; A still OK
    // to leave in flight — vmcnt(4) forces csg/csb + own B(0) complete).
    STAGE_B(0)
    STAGE_A(0)
    asm volatile("s_waitcnt vmcnt(4)" ::: "memory");
    __builtin_amdgcn_s_barrier();
    asm volatile("" ::: "memory");
    __builtin_amdgcn_sched_barrier(0);

    f32x4 acc[4] = {{0.f,0.f,0.f,0.f},{0.f,0.f,0.f,0.f},{0.f,0.f,0.f,0.f},{0.f,0.f,0.f,0.f}};
    float s1a = 0.f, s2a = 0.f;

#pragma unroll 1
    for (int ci = 0; ci < 16; ++ci) {
        // stage chunk ci+1 (7 vmem: 3 B then 4 A)
        if (ci < 15) {
            STAGE_B(ci + 1)
            STAGE_A(ci + 1)
            // A(ci) done: younger ops = 3 B(ci+1) + 4 A(ci+1) = 7
            WAITV(7);
        } else {
            WAITV(0);
        }
        // compute 2 k-steps from Abuf[ci&1]/Bbuf[ci&1]
        const float* Ab = smem + A_F + (ci & 1) * 8192 + wv * 1024;
        const float* Bb = smem + B_F + (ci & 1) * 6144;
#pragma unroll
        for (int st = 0; st < 2; ++st) {
            const f32x4 a00 = *(const f32x4*)(Ab + st * 512 + lane * 4);
            const f32x4 a01 = *(const f32x4*)(Ab + st * 512 + 256 + lane * 4);
            short8 AH0, AM0, AL0;
            split8(a00, a01, AH0, AM0, AL0, s1a, s2a);
            const float* Bs = Bb + st * 3072;
#pragma unroll
            for (int n = 0; n < 4; ++n) {
                const uint4 bh = *(const uint4*)(Bs + n * 256 + lane * 4);
                const uint4 bm = *(const uint4*)(Bs + 1024 + n * 256 + lane * 4);
                const uint4 bl = *(const uint4*)(Bs + 2048 + n * 256 + lane * 4);
                MFMA6(acc[n], AH0, AM0, AL0, bh, bm, bl);
            }
        }
        if (ci < 15) {
            // publish B(ci+1): own 3 B done (younger = 4 A(ci+1)); A stays
            // in flight across the barrier.
            BARRIER_PUB();
        }
    }
    __syncthreads();   // full drain; staging buffers dead -> epilogue aliases

    // LN-stat q-reduction: lane (q,c) holds k-partials for token tokw+c;
    // xor 16/32 combines the 4 q replicas -> full-K stats at lane c.
    s1a += __shfl_xor(s1a, 16, 64); s1a += __shfl_xor(s1a, 32, 64);
    s2a += __shfl_xor(s2a, 16, 64); s2a += __shfl_xor(s2a, 32, 64);

    if (t < 16) cntl[t] = 0.f;
    if (t < 256) *(float4*)(w2l + t * 4) = *(const float4*)(W2 + t * 4);

    // stats redistribution (token tt stats live at lane tt) + LN fold +
    // exact GELU, straight from accumulator registers -> h to LDS.
    {
        float* hw = hlds + wv * 1040;
#pragma unroll
        for (int r = 0; r < 4; ++r) {
            const int tt = q * 4 + r;
            const float S1A = __shfl(s1a, tt, 64), S2A = __shfl(s2a, tt, 64);
            const float muA = S1A * (1.0f / 1024.0f);
            const float rsA = 1.0f / sqrtf(S2A * (1.0f / 1024.0f) - muA * muA + LN_EPS);
#pragma unroll
            for (int n = 0; n < 4; ++n) {
                const float preA = rsA * (acc[n][r] - muA * csg[n]) + csb[n];
                hw[tt * 65 + n * 16 + c] =
                    0.5f * preA * (1.0f + erff(preA * 0.70710678118654752f));
            }
        }
    }
    __syncthreads();

    // logits: thread -> (token m2 = t>>2, 4 nb cols)
    {
        const int m2 = t >> 2, o = (t & 3) * 4;
        const float* hrow = hlds + (m2 >> 4) * 1040 + (m2 & 15) * 65;
        f32x4 L0 = {0.f, 0.f, 0.f, 0.f};
#pragma unroll 8
        for (int j = 0; j < 64; ++j) {
            L0 += *(const f32x4*)(w2l + j * 16 + o) * hrow[j];
        }
        *(f32x4*)(llds + m2 * 20 + o) = L0 * 0.5f;   // /TEMP
    }
    __syncthreads();

    // softmax + top-2 + outputs (one thread per token; 128 tokens/block)
    if (t < 128) {
        float p[16];
        float mx = -1e30f;
#pragma unroll
        for (int i = 0; i < NB; ++i) { p[i] = llds[t * 20 + i]; mx = fmaxf(mx, p[i]); }
        float ssum = 0.f;
#pragma unroll
        for (int i = 0; i < NB; ++i) { p[i] = expf(p[i] - mx); ssum += p[i]; }
        const float inv = 1.0f / ssum;
#pragma unroll
        for (int i = 0; i < NB; ++i) { p[i] *= inv; llds[t * 20 + i] = p[i]; }

        float* po = out + (size_t)(tok0 + t) * NB;
#pragma unroll
        for (int u = 0; u < 4; ++u) {
            float4 v; v.x = p[u*4]; v.y = p[u*4+1]; v.z = p[u*4+2]; v.w = p[u*4+3];
            *(float4*)(po + u * 4) = v;
        }

        float b0 = -1.f, b1 = -1.f;
        int i0 = 0, i1 = 0;
#pragma unroll
        for (int i = 0; i < NB; ++i) {
            if (p[i] > b0)      { b1 = b0; i1 = i0; b0 = p[i]; i0 = i; }
            else if (p[i] > b1) { b1 = p[i]; i1 = i; }
        }
        const float wsum = b0 + b1 + 1e-8f;
        out[IDX_OFF + (size_t)(tok0 + t) * 2]     = (float)i0;
        out[IDX_OFF + (size_t)(tok0 + t) * 2 + 1] = (float)i1;
        out[WT_OFF + (size_t)(tok0 + t) * 2]      = b0 / wsum;
        out[WT_OFF + (size_t)(tok0 + t) * 2 + 1]  = b1 / wsum;
        atomicAdd(&cntl[i0], 1.0f);
        atomicAdd(&cntl[i1], 1.0f);
    }
    __syncthreads();

    // per-block partials (plain stores; aux reads after dispatch boundary)
    if (t < 16) {
        float ps = 0.f;
        for (int m = 0; m < 128; ++m) ps += llds[m * 20 + t];
        part[(size_t)blockIdx.x * 32 + t]      = cntl[t];
        part[(size_t)blockIdx.x * 32 + 16 + t] = ps;
    }
}

__global__ void aux_kernel(const float* __restrict__ part,
                           float* __restrict__ gacc,
                           float* __restrict__ out) {
    __shared__ float red[8][32];
    __shared__ float flag;
    const int t = threadIdx.x;          // 256
    const int b = blockIdx.x;           // 16 blocks x 16 rows (256 total)
    const int i = t & 31, rr = t >> 5;  // rr 0..7
    const int r0 = b * 16 + rr;
    red[rr][i] = part[(size_t)r0 * 32 + i] + part[(size_t)(r0 + 8) * 32 + i];
    __syncthreads();
    if (t < 32) {
        float tot = 0.f;
#pragma unroll
        for (int p = 0; p < 8; ++p) tot += red[p][t];
        atomicAdd(&gacc[t], tot);
    }
    __syncthreads();
    if (t == 0) {
        __threadfence();
        const unsigned int old = atomicAdd((unsigned int*)(gacc + 32), 1u);
        flag = (old == 15u) ? 1.f : 0.f;
    }
    __syncthreads();
    if (flag != 0.f) {
        if (t < 32) red[0][t] = atomicAdd(&gacc[t], 0.0f);   // coherent read
        __syncthreads();
        if (t == 0) {
            float a = 0.f;
            for (int k = 0; k < NB; ++k) {
                const float f = red[0][k] / (65536.0f + 1e-8f);
                const float P = red[0][16 + k] * (1.0f / 32768.0f);
                a += f * P;
            }
            out[AUX_OFF] = 16.0f * a;
        }
    }
}

extern "C" void kernel_launch(void* const* d_in, const int* in_sizes, int n_in,
                              void* d_out, int out_size, void* d_ws, size_t ws_size,
                              hipStream_t stream) {
    const float* x     = (const float*)d_in[0];
    const float* gamma = (const float*)d_in[1];
    const float* beta  = (const float*)d_in[2];
    const float* W1    = (const float*)d_in[3];
    const float* W2    = (const float*)d_in[4];
    float* out = (float*)d_out;
    float* ws  = (float*)d_ws;

    (void)hipMemsetAsync(ws, 0, 192 * sizeof(float), stream);  // accums + counter + cs
    pack_kernel<<<32, 256, 0, stream>>>(W1, gamma, beta, ws);
    router_main<<<NTOK / 128, 512, 0, stream>>>(x, ws, (const unsigned int*)(ws + BP_F),
                                                W2, ws + PART_F, out);
    aux_kernel<<<16, 256, 0, stream>>>(ws + PART_F, ws, out);
}

// Round 5
// 222.558 us; speedup vs baseline: 1.0227x; 1.0227x over previous
//
#include <hip/hip_runtime.h>
#include <math.h>

typedef __attribute__((ext_vector_type(8))) short short8;
typedef __attribute__((ext_vector_type(4))) float f32x4;

#define NTOK 32768          // B*L
#define DDIM 1024
#define HDIM 64
#define NB 16
#define LN_EPS 1e-5f

#define IDX_OFF ((size_t)NTOK * NB)            // 524288
#define AUX_OFF (IDX_OFF + (size_t)NTOK * 2)   // 589824
#define WT_OFF  (AUX_OFF + 1)                  // 589825

// ws (float) layout:
//   [0:16)  cnt accum   [16:32) Psum accum   [32] completion counter (uint)
//   [64:128)  csg = colsum(gamma*W1)   [128:192) csb = colsum(beta*W1)
//   [4352 : +98304)   B-pack: 3 terms x 32 ksteps x 4 ntiles x 64 lanes x 4 dw
//   [102656 : +8192)  per-block partials: 256 rows x [0:16 cnt | 16:32 Psum]
#define CS_F   64
#define BP_F   4352
#define PART_F 102656

__device__ __forceinline__ short8 as_s8(uint4 u) {
    union { uint4 u; short8 s; } x; x.u = u; return x.s;
}

__device__ __forceinline__ f32x4 ntload4(const float* p) {
    return __builtin_nontemporal_load((const f32x4*)p);
}

// async global->LDS, 16B per lane. LDS dest is wave-uniform base + lane*16;
// global src is per-lane.
__device__ __forceinline__ void gld16(const void* g, float* l) {
    __builtin_amdgcn_global_load_lds(
        (const __attribute__((address_space(1))) void*)g,
        (__attribute__((address_space(3))) void*)l, 16, 0, 0);
}

// Fused: B-pack (3-term bf16 split of gamma*W1, MFMA B-frag order) + final
// colsums of gamma*W1 / beta*W1 via atomicAdd (ws[CS_F..] pre-zeroed).
__global__ void pack_kernel(const float* __restrict__ W1,
                            const float* __restrict__ gamma,
                            const float* __restrict__ beta,
                            float* __restrict__ ws) {
    __shared__ float sg[4][64];
    __shared__ float sb[4][64];
    const int s = blockIdx.x;           // k-range 32s..32s+31
    const int t = threadIdx.x;          // 256

    {   // cs partials
        const int j = t & 63, p = t >> 6;
        float ag = 0.f, ab = 0.f;
        for (int kk = 0; kk < 8; ++kk) {
            const int k = s * 32 + p * 8 + kk;
            const float w = W1[k * HDIM + j];
            ag += gamma[k] * w;
            ab += beta[k] * w;
        }
        sg[p][j] = ag;
        sb[p][j] = ab;
    }

    {   // B pack
        unsigned int* bp = (unsigned int*)(ws + BP_F);
        const int n = t >> 6;           // n-tile
        const int l = t & 63;           // frag lane
        const int q = l >> 4, c = l & 15;
        const int col = n * 16 + c;
        unsigned int uh[8], um[8], ul[8];
#pragma unroll
        for (int j = 0; j < 8; ++j) {
            const int k = s * 32 + q * 8 + j;
            const float w = gamma[k] * W1[k * HDIM + col];
            const unsigned int hb = __float_as_uint(w) & 0xFFFF0000u;
            const float r = w - __uint_as_float(hb);
            const unsigned int mb = __float_as_uint(r) & 0xFFFF0000u;
            const float r2 = r - __uint_as_float(mb);
            const unsigned int lb = __float_as_uint(r2) & 0xFFFF0000u;
            uh[j] = hb >> 16; um[j] = mb >> 16; ul[j] = lb >> 16;
        }
        const int base = ((s * 4 + n) * 64 + l) * 4;
#pragma unroll
        for (int d = 0; d < 4; ++d) {
            bp[base + d]         = uh[2 * d] | (uh[2 * d + 1] << 16);
            bp[32768 + base + d] = um[2 * d] | (um[2 * d + 1] << 16);
            bp[65536 + base + d] = ul[2 * d] | (ul[2 * d + 1] << 16);
        }
    }
    __syncthreads();
    if (t < 64) {
        atomicAdd(&ws[CS_F + t],      sg[0][t] + sg[1][t] + sg[2][t] + sg[3][t]);
        atomicAdd(&ws[CS_F + 64 + t], sb[0][t] + sb[1][t] + sb[2][t] + sb[3][t]);
    }
}

// 3-term truncated-bf16 split of 8 floats + LN-stat accumulation.
__device__ __forceinline__ void split8(const f32x4 a0, const f32x4 a1,
                                       short8& AH, short8& AM, short8& AL,
                                       float& s1, float& s2) {
    const float v[8] = {a0.x, a0.y, a0.z, a0.w, a1.x, a1.y, a1.z, a1.w};
    unsigned int ph[4], pm[4], pl[4];
#pragma unroll
    for (int d = 0; d < 4; ++d) {
        const float v0 = v[2 * d], v1 = v[2 * d + 1];
        const unsigned int h0 = __float_as_uint(v0) & 0xFFFF0000u;
        const unsigned int h1 = __float_as_uint(v1) & 0xFFFF0000u;
        const float r0 = v0 - __uint_as_float(h0);
        const float r1 = v1 - __uint_as_float(h1);
        const unsigned int m0 = __float_as_uint(r0) & 0xFFFF0000u;
        const unsigned int m1 = __float_as_uint(r1) & 0xFFFF0000u;
        const float q0 = r0 - __uint_as_float(m0);
        const float q1 = r1 - __uint_as_float(m1);
        ph[d] = (h0 >> 16) | h1;
        pm[d] = (m0 >> 16) | m1;
        pl[d] = (__float_as_uint(q0) >> 16) | (__float_as_uint(q1) & 0xFFFF0000u);
        s1 += v0 + v1;
        s2 = fmaf(v0, v0, fmaf(v1, v1, s2));
    }
    AH = as_s8(make_uint4(ph[0], ph[1], ph[2], ph[3]));
    AM = as_s8(make_uint4(pm[0], pm[1], pm[2], pm[3]));
    AL = as_s8(make_uint4(pl[0], pl[1], pl[2], pl[3]));
}

#define MFMA6(ACC, AH, AM, AL, BH, BM, BL)                                        \
    ACC = __builtin_amdgcn_mfma_f32_16x16x32_bf16(AH, as_s8(BH), ACC, 0, 0, 0);   \
    ACC = __builtin_amdgcn_mfma_f32_16x16x32_bf16(AH, as_s8(BM), ACC, 0, 0, 0);   \
    ACC = __builtin_amdgcn_mfma_f32_16x16x32_bf16(AM, as_s8(BH), ACC, 0, 0, 0);   \
    ACC = __builtin_amdgcn_mfma_f32_16x16x32_bf16(AH, as_s8(BL), ACC, 0, 0, 0);   \
    ACC = __builtin_amdgcn_mfma_f32_16x16x32_bf16(AM, as_s8(BM), ACC, 0, 0, 0);   \
    ACC = __builtin_amdgcn_mfma_f32_16x16x32_bf16(AL, as_s8(BH), ACC, 0, 0, 0);

// publish barrier: B(ci+1) gld16 (issued a full compute-phase earlier) must
// be in LDS; A ds_writes (wave-local) must be retired. rule-#18 fences.
#define PUB()                                                       \
    asm volatile("s_waitcnt vmcnt(0) lgkmcnt(0)" ::: "memory");     \
    __builtin_amdgcn_s_barrier();                                   \
    __builtin_amdgcn_sched_barrier(0)

// Block = 128 tokens, 8 waves; wave wv owns tokens [wv*16,+16), full K=1024
// as 16 chunks x 2 k-steps. NEW vs round 4: A (the x-stream, 128 MB) is
// loaded COALESCED — lane-linear, 16 lanes cover one token's contiguous
// 256 B chunk-row (4 fully-consumed 64B lines/instr) — into registers
// (T14 issue-early/write-late), then ds_write'd into a padded per-wave LDS
// tile [16 tok][68] (stride 68 => b128 banks equivalent to linear; 2-way
// max = free). All five prior variants loaded x at the MFMA-fragment
// mapping: 16 B/lane at 4 KB token stride = 32 scattered lines per
// instruction, which saturates the per-CU miss-tracking resources at ~2
// instructions in flight and caps fetch at the invariant ~850 GB/s
// (occupancy- and pipeline-depth-independent, as rounds 1-4 showed).
// A is wave-private: no barrier on the A path at all. B keeps the publish
// barrier; its vmcnt(0) covers 3 L2-resident loads issued one full compute
// phase earlier.
#define A_F 0
#define A_BSTRIDE 8704      // per-buffer floats: 8 waves x 1088
#define B_F 17408
#define B_BSTRIDE 6144
__global__ __launch_bounds__(512, 2)
void router_main(const float* __restrict__ x,
                 const float* __restrict__ ws_ro,       // csg/csb
                 const unsigned int* __restrict__ bp,   // packed B frags
                 const float* __restrict__ W2,
                 float* __restrict__ part,
                 float* __restrict__ out) {
    __shared__ __align__(16) float smem[29696];   // 116 KB -> 1 block/CU
    // epilogue aliases (valid only after the post-loop __syncthreads):
    float* hlds = smem;            // [8 waves][16 tok][65] = 8320
    float* w2l  = smem + 8320;     // [64][16] = 1024
    float* llds = smem + 9344;     // [128 tok][20] = 2560
    float* cntl = smem + 11904;    // [16]

    const int t    = threadIdx.x;
    const int wv   = t >> 6;                 // 0..7
    const int lane = t & 63;
    const int q = lane >> 4, c = lane & 15;  // MFMA frag role AND staging
    const int tok0 = blockIdx.x * 128;       //   role (g=q, m=c)
    const int tokw = tok0 + wv * 16;

    // per-lane colsum constants (col = n*16 + c)
    float csg[4], csb[4];
#pragma unroll
    for (int n = 0; n < 4; ++n) {
        csg[n] = ws_ro[CS_F + n * 16 + c];
        csb[n] = ws_ro[CS_F + 64 + n * 16 + c];
    }

    const int bidx0 = wv * 3;
    // coalesced A source: lane covers token (tokw + q) + j*4, bytes c*16..
    const float* xA = x + (size_t)(tokw + q) * DDIM + c * 4;
    // A LDS bases (padded stride 68)
    float* awb       = smem + A_F + wv * 1088 + q * 68 + c * 4;   // write
    const float* arb = smem + A_F + wv * 1088 + c * 68 + q * 8;   // read

#define STAGE_B(CI)                                                              \
    {                                                                            \
        float* dst = smem + B_F + ((CI) & 1) * B_BSTRIDE;                        \
        _Pragma("unroll")                                                        \
        for (int i = 0; i < 3; ++i) {                                            \
            const int idx = bidx0 + i;                                           \
            const int st = (idx >= 12) ? 1 : 0;                                  \
            const int rem = idx - st * 12;                                       \
            const int term = rem >> 2, n = rem & 3;                              \
            gld16(bp + term * 32768 + (2 * (CI) + st) * 1024 + n * 256 + lane*4, \
                  dst + st * 3072 + term * 1024 + n * 256);                      \
        }                                                                        \
    }
#define STAGE_A(CI)                                                              \
    {                                                                            \
        const float* srcA = xA + (CI) * 64;                                      \
        ar0 = ntload4(srcA);                                                     \
        ar1 = ntload4(srcA + 4096);                                              \
        ar2 = ntload4(srcA + 8192);                                              \
        ar3 = ntload4(srcA + 12288);                                             \
    }
#define DS_WRITE_A(CI)                                                           \
    {                                                                            \
        float* dw = awb + ((CI) & 1) * A_BSTRIDE;                                \
        *(f32x4*)(dw)       = ar0;                                               \
        *(f32x4*)(dw + 272) = ar1;                                               \
        *(f32x4*)(dw + 544) = ar2;                                               \
        *(f32x4*)(dw + 816) = ar3;                                               \
    }
#define COMPUTE(CI)                                                              \
    {                                                                            \
        const float* Ab = arb + ((CI) & 1) * A_BSTRIDE;                          \
        const float* Bb = smem + B_F + ((CI) & 1) * B_BSTRIDE;                   \
        _Pragma("unroll")                                                        \
        for (int st = 0; st < 2; ++st) {                                         \
            const f32x4 a00 = *(const f32x4*)(Ab + st * 32);                     \
            const f32x4 a01 = *(const f32x4*)(Ab + st * 32 + 4);                 \
            short8 AH0, AM0, AL0;                                                \
            split8(a00, a01, AH0, AM0, AL0, s1a, s2a);                           \
            const float* Bs = Bb + st * 3072;                                    \
            _Pragma("unroll")                                                    \
            for (int n = 0; n < 4; ++n) {                                        \
                const uint4 bh = *(const uint4*)(Bs + n * 256 + lane * 4);       \
                const uint4 bm = *(const uint4*)(Bs + 1024 + n * 256 + lane*4);  \
                const uint4 bl = *(const uint4*)(Bs + 2048 + n * 256 + lane*4);  \
                MFMA6(acc[n], AH0, AM0, AL0, bh, bm, bl);                        \
            }                                                                    \
        }                                                                        \
    }

    f32x4 acc[4] = {{0.f,0.f,0.f,0.f},{0.f,0.f,0.f,0.f},{0.f,0.f,0.f,0.f},{0.f,0.f,0.f,0.f}};
    float s1a = 0.f, s2a = 0.f;
    f32x4 ar0, ar1, ar2, ar3;

    // prologue: chunk 0 — A coalesced->regs->LDS (compiler inserts the
    // A-reg waits), B via gld16, then publish.
    STAGE_A(0)
    STAGE_B(0)
    DS_WRITE_A(0)
    PUB();

#pragma unroll 1
    for (int ci = 0; ci < 16; ++ci) {
        if (ci < 15) {
            STAGE_A(ci + 1)
            STAGE_B(ci + 1)
            __builtin_amdgcn_sched_barrier(0);   // pin staging before compute
        }
        COMPUTE(ci)
        if (ci < 15) {
            DS_WRITE_A(ci + 1)
            PUB();
        }
    }
    __syncthreads();   // full drain; staging buffers dead -> epilogue aliases

    // LN-stat q-reduction: lane (q,c) holds k-partials for token tokw+c;
    // xor 16/32 combines the 4 q replicas -> full-K stats at lane c.
    s1a += __shfl_xor(s1a, 16, 64); s1a += __shfl_xor(s1a, 32, 64);
    s2a += __shfl_xor(s2a, 16, 64); s2a += __shfl_xor(s2a, 32, 64);

    if (t < 16) cntl[t] = 0.f;
    if (t < 256) *(float4*)(w2l + t * 4) = *(const float4*)(W2 + t * 4);

    // stats redistribution (token tt stats live at lane tt) + LN fold +
    // exact GELU, straight from accumulator registers -> h to LDS.
    {
        float* hw = hlds + wv * 1040;
#pragma unroll
        for (int r = 0; r < 4; ++r) {
            const int tt = q * 4 + r;
            const float S1A = __shfl(s1a, tt, 64), S2A = __shfl(s2a, tt, 64);
            const float muA = S1A * (1.0f / 1024.0f);
            const float rsA = 1.0f / sqrtf(S2A * (1.0f / 1024.0f) - muA * muA + LN_EPS);
#pragma unroll
            for (int n = 0; n < 4; ++n) {
                const float preA = rsA * (acc[n][r] - muA * csg[n]) + csb[n];
                hw[tt * 65 + n * 16 + c] =
                    0.5f * preA * (1.0f + erff(preA * 0.70710678118654752f));
            }
        }
    }
    __syncthreads();

    // logits: thread -> (token m2 = t>>2, 4 nb cols)
    {
        const int m2 = t >> 2, o = (t & 3) * 4;
        const float* hrow = hlds + (m2 >> 4) * 1040 + (m2 & 15) * 65;
        f32x4 L0 = {0.f, 0.f, 0.f, 0.f};
#pragma unroll 8
        for (int j = 0; j < 64; ++j) {
            L0 += *(const f32x4*)(w2l + j * 16 + o) * hrow[j];
        }
        *(f32x4*)(llds + m2 * 20 + o) = L0 * 0.5f;   // /TEMP
    }
    __syncthreads();

    // softmax + top-2 + outputs (one thread per token; 128 tokens/block)
    if (t < 128) {
        float p[16];
        float mx = -1e30f;
#pragma unroll
        for (int i = 0; i < NB; ++i) { p[i] = llds[t * 20 + i]; mx = fmaxf(mx, p[i]); }
        float ssum = 0.f;
#pragma unroll
        for (int i = 0; i < NB; ++i) { p[i] = expf(p[i] - mx); ssum += p[i]; }
        const float inv = 1.0f / ssum;
#pragma unroll
        for (int i = 0; i < NB; ++i) { p[i] *= inv; llds[t * 20 + i] = p[i]; }

        float* po = out + (size_t)(tok0 + t) * NB;
#pragma unroll
        for (int u = 0; u < 4; ++u) {
            float4 v; v.x = p[u*4]; v.y = p[u*4+1]; v.z = p[u*4+2]; v.w = p[u*4+3];
            *(float4*)(po + u * 4) = v;
        }

        float b0 = -1.f, b1 = -1.f;
        int i0 = 0, i1 = 0;
#pragma unroll
        for (int i = 0; i < NB; ++i) {
            if (p[i] > b0)      { b1 = b0; i1 = i0; b0 = p[i]; i0 = i; }
            else if (p[i] > b1) { b1 = p[i]; i1 = i; }
        }
        const float wsum = b0 + b1 + 1e-8f;
        out[IDX_OFF + (size_t)(tok0 + t) * 2]     = (float)i0;
        out[IDX_OFF + (size_t)(tok0 + t) * 2 + 1] = (float)i1;
        out[WT_OFF + (size_t)(tok0 + t) * 2]      = b0 / wsum;
        out[WT_OFF + (size_t)(tok0 + t) * 2 + 1]  = b1 / wsum;
        atomicAdd(&cntl[i0], 1.0f);
        atomicAdd(&cntl[i1], 1.0f);
    }
    __syncthreads();

    // per-block partials (plain stores; aux reads after dispatch boundary)
    if (t < 16) {
        float ps = 0.f;
        for (int m = 0; m < 128; ++m) ps += llds[m * 20 + t];
        part[(size_t)blockIdx.x * 32 + t]      = cntl[t];
        part[(size_t)blockIdx.x * 32 + 16 + t] = ps;
    }
}

__global__ void aux_kernel(const float* __restrict__ part,
                           float* __restrict__ gacc,
                           float* __restrict__ out) {
    __shared__ float red[8][32];
    __shared__ float flag;
    const int t = threadIdx.x;          // 256
    const int b = blockIdx.x;           // 16 blocks x 16 rows (256 total)
    const int i = t & 31, rr = t >> 5;  // rr 0..7
    const int r0 = b * 16 + rr;
    red[rr][i] = part[(size_t)r0 * 32 + i] + part[(size_t)(r0 + 8) * 32 + i];
    __syncthreads();
    if (t < 32) {
        float tot = 0.f;
#pragma unroll
        for (int p = 0; p < 8; ++p) tot += red[p][t];
        atomicAdd(&gacc[t], tot);
    }
    __syncthreads();
    if (t == 0) {
        __threadfence();
        const unsigned int old = atomicAdd((unsigned int*)(gacc + 32), 1u);
        flag = (old == 15u) ? 1.f : 0.f;
    }
    __syncthreads();
    if (flag != 0.f) {
        if (t < 32) red[0][t] = atomicAdd(&gacc[t], 0.0f);   // coherent read
        __syncthreads();
        if (t == 0) {
            float a = 0.f;
            for (int k = 0; k < NB; ++k) {
                const float f = red[0][k] / (65536.0f + 1e-8f);
                const float P = red[0][16 + k] * (1.0f / 32768.0f);
                a += f * P;
            }
            out[AUX_OFF] = 16.0f * a;
        }
    }
}

extern "C" void kernel_launch(void* const* d_in, const int* in_sizes, int n_in,
                              void* d_out, int out_size, void* d_ws, size_t ws_size,
                              hipStream_t stream) {
    const float* x     = (const float*)d_in[0];
    const float* gamma = (const float*)d_in[1];
    const float* beta  = (const float*)d_in[2];
    const float* W1    = (const float*)d_in[3];
    const float* W2    = (const float*)d_in[4];
    float* out = (float*)d_out;
    float* ws  = (float*)d_ws;

    (void)hipMemsetAsync(ws, 0, 192 * sizeof(float), stream);  // accums + counter + cs
    pack_kernel<<<32, 256, 0, stream>>>(W1, gamma, beta, ws);
    router_main<<<NTOK / 128, 512, 0, stream>>>(x, ws, (const unsigned int*)(ws + BP_F),
                                                W2, ws + PART_F, out);
    aux_kernel<<<16, 256, 0, stream>>>(ws + PART_F, ws, out);
}